// Round 3
// baseline (191.470 us; speedup 1.0000x reference)
//
#include <hip/hip_runtime.h>
#include <math.h>

// Problem constants: B=64, N=512, d=64
#define NB 64
#define NN 512
#define ND 64

#define LOG2E 1.4426950408889634f
#define LN2   0.6931471805599453f
#define RING  8                       // in-register prefetch depth (from LDS)
#define SD    592                     // padded step count per wave plane
#define NINF  __int_as_float(0xFF800000u)   // -inf

typedef __attribute__((ext_vector_type(8))) short  bf16x8;  // 8 bf16 in 4 VGPRs
typedef __attribute__((ext_vector_type(4))) float  f32x4;

// fp32 -> bf16 bits, round-to-nearest-even (inputs are finite)
static __device__ __forceinline__ unsigned short f2bf(float f) {
    unsigned u = __float_as_uint(f);
    u += 0x7FFFu + ((u >> 16) & 1u);
    return (unsigned short)(u >> 16);
}

// ---------------------------------------------------------------------------
// Kernel 0 (pack): X,Y (f32 row-major) -> bf16 in MFMA-fragment order, plus
// fp32 row norms (R12/R13-proven, unchanged).
// ---------------------------------------------------------------------------
__global__ __launch_bounds__(256) void pack_kernel(const float* __restrict__ X,
                                                   const float* __restrict__ Y,
                                                   unsigned short* __restrict__ Xp,
                                                   unsigned short* __restrict__ Yp,
                                                   float* __restrict__ nx,
                                                   float* __restrict__ ny) {
    const int gid = blockIdx.x * 256 + threadIdx.x;   // row id, 0..NB*NN-1
    const float* src;
    unsigned short* dst;
    float* ndst;
    if (blockIdx.y == 0) { src = X + (size_t)gid * ND; dst = Xp; ndst = nx; }
    else                 { src = Y + (size_t)gid * ND; dst = Yp; ndst = ny; }

    float v[ND];
    float s = 0.f;
    #pragma unroll
    for (int k = 0; k < ND; k += 4) {
        float4 f = *(const float4*)(src + k);
        v[k] = f.x; v[k + 1] = f.y; v[k + 2] = f.z; v[k + 3] = f.w;
        s += f.x * f.x + f.y * f.y + f.z * f.z + f.w * f.w;
    }
    ndst[gid] = s;

    const int b  = gid >> 9;
    const int i  = gid & 511;
    const int it = i >> 4;             // 16-row tile
    const int lm = i & 15;             // row within tile
    #pragma unroll
    for (int h = 0; h < 2; ++h) {
        #pragma unroll
        for (int q = 0; q < 4; ++q) {
            unsigned w[4];
            #pragma unroll
            for (int m = 0; m < 4; ++m) {
                const int c = h * 32 + q * 8 + 2 * m;
                w[m] = (unsigned)f2bf(v[c]) | ((unsigned)f2bf(v[c + 1]) << 16);
            }
            uint4 pkt; pkt.x = w[0]; pkt.y = w[1]; pkt.z = w[2]; pkt.w = w[3];
            *(uint4*)(dst + ((((size_t)b * 32 + it) * 2 + h) << 9)
                          + (size_t)(q * 16 + lm) * 8) = pkt;
        }
    }
}

// ---------------------------------------------------------------------------
// Kernel 1 (MFMA): W[b][i][j] = bf16( exp2(16 - log2e*||X[b][i]-Y[b][j]||) )
// R16: back to the R14 PLANE-MAJOR anti-diagonal layout Wd[plane][s][t]
// (plane = b*2 + wv, uint2 = 4 bf16 rows j0..j0+3, j0 = wv*256+4t, column
// c = i+1, step s = i + t). This layout was numerically validated in R14
// (absmax 0.0) and gives the dtw loader waves fully-contiguous 16KB reads.
// ---------------------------------------------------------------------------
__global__ __launch_bounds__(256) void cdist_kernel(const unsigned short* __restrict__ Xp,
                                                    const unsigned short* __restrict__ Yp,
                                                    const float* __restrict__ nx,
                                                    const float* __restrict__ ny,
                                                    uint2* __restrict__ Wd) {
    const int b  = blockIdx.z;
    const int ib = blockIdx.x * 128;   // i base (X rows)
    const int jb = blockIdx.y * 128;   // j base (Y rows)
    const int t  = threadIdx.x;

    const int wave = t >> 6;
    const int wi   = (wave & 1) * 64;   // i offset of this wave's 64x64 tile
    const int wj   = (wave >> 1) * 64;  // j offset
    const int lane = t & 63;
    const int lm   = lane & 15;
    const int quad = lane >> 4;

    f32x4 acc[4][4];
    #pragma unroll
    for (int mt = 0; mt < 4; ++mt)
        #pragma unroll
        for (int nt = 0; nt < 4; ++nt)
            acc[mt][nt] = (f32x4){0.f, 0.f, 0.f, 0.f};

    const int jt0 = (jb + wj) >> 4;    // Y tile base
    const int it0 = (ib + wi) >> 4;    // X tile base

    #pragma unroll
    for (int h = 0; h < 2; ++h) {
        bf16x8 Af[4], Bf[4];
        #pragma unroll
        for (int mt = 0; mt < 4; ++mt)   // A from Y tiles (m = j dim)
            Af[mt] = *(const bf16x8*)(Yp
                + ((((size_t)b * 32 + jt0 + mt) * 2 + h) << 9) + (size_t)lane * 8);
        #pragma unroll
        for (int nt = 0; nt < 4; ++nt)   // B from X tiles (n = i dim)
            Bf[nt] = *(const bf16x8*)(Xp
                + ((((size_t)b * 32 + it0 + nt) * 2 + h) << 9) + (size_t)lane * 8);
        #pragma unroll
        for (int mt = 0; mt < 4; ++mt)
            #pragma unroll
            for (int nt = 0; nt < 4; ++nt)
                acc[mt][nt] = __builtin_amdgcn_mfma_f32_16x16x32_bf16(
                    Af[mt], Bf[nt], acc[mt][nt], 0, 0, 0);
    }

    float nxv[4];
    float4 nyv[4];
    #pragma unroll
    for (int nt = 0; nt < 4; ++nt)
        nxv[nt] = nx[(size_t)b * NN + ib + wi + nt * 16 + lm];
    #pragma unroll
    for (int mt = 0; mt < 4; ++mt)
        nyv[mt] = *(const float4*)(ny + (size_t)b * NN + jb + wj + mt * 16 + quad * 4);

    #pragma unroll
    for (int nt = 0; nt < 4; ++nt) {
        const int i = ib + wi + nt * 16 + lm;        // column index c-1
        #pragma unroll
        for (int mt = 0; mt < 4; ++mt) {
            const int j0 = jb + wj + mt * 16 + quad * 4;  // first of 4 rows
            const int wv = j0 >> 8;                   // DP wave (0: j<256)
            const int tt = (j0 >> 2) & 63;            // DP lane
            const float* nyp = (const float*)&nyv[mt];
            unsigned a[4];
            #pragma unroll
            for (int r = 0; r < 4; ++r) {
                float d2 = nyp[r] + nxv[nt] - 2.0f * acc[mt][nt][r];
                float w  = __builtin_amdgcn_exp2f(16.0f - LOG2E * sqrtf(fmaxf(d2, 0.f)));
                a[r] = __float_as_uint(w) + 0x8000u;   // round-half-up to bf16
            }
            uint2 pkt;
            pkt.x = (a[0] >> 16) | (a[1] & 0xFFFF0000u);
            pkt.y = (a[2] >> 16) | (a[3] & 0xFFFF0000u);
            // plane-major: Wd[plane][s][t]; cells with c outside [1,512] are
            // never written and only consumed under the guarded path.
            Wd[((size_t)(b * 2 + wv) * SD + (size_t)(i + tt)) * 64 + tt] = pkt;
        }
    }
}

// ---------------------------------------------------------------------------
// Kernel 2: soft-DTW DP, exp-domain chain (R11-R13-proven math).
// R16: 4 waves/block. Waves 0/1 = DP (identical math to R13/R14); waves 2/3
// stream W plane data global->LDS ahead of consumption. DP refill is now a
// single ds_read_b64 from a private 64KB LDS ring (4 slots x 32 steps x
// 512B), decoupling HBM/L2 latency from the serial DP chain.
//   Slot schedule (mod 4, 32-step walls): consumer wall w reads slots
//   {w, w+1}; its loader writes slot {w+2}. Wave 1 lags 4 walls; its loader
//   is offset -2 walls. Pre-loop: loaders fill steps [0,64) (slots 0,1).
//   h0 preload: odd walls 3..19, values written by wave0 >= 1 step earlier
//   (same margin as the proven 64-step schedule).
// ---------------------------------------------------------------------------
static __device__ __forceinline__ float dpp_shr1(float x, float old) {
    return __int_as_float(__builtin_amdgcn_update_dpp(
        __float_as_int(old), __float_as_int(x), 0x138, 0xf, 0xf, false));
}
static __device__ __forceinline__ float dpp_shl1(float x) {
    return __int_as_float(__builtin_amdgcn_update_dpp(
        0, __float_as_int(x), 0x130, 0xf, 0xf, false));
}

static __device__ __forceinline__ void dtw_step4(
    bool W1, bool DOACT, bool DOGUARD, bool DOREN,
    int ss, int u, int t, const uint2 (* __restrict__ P)[64],
    uint2* ring, float* L, float& diagHold, float& h, float& Otf,
    float& hbuf, float* __restrict__ h0)
{
    // intra-wave handoff: lane t gets lane t-1's h (lane 0: -inf)
    float recvH = dpp_shr1(h, NINF);
    if (W1) {
        recvH = (t == 0) ? hbuf : recvH;   // lane 0: cross-wave value from LDS
        hbuf  = dpp_shl1(hbuf);            // rotate: next step's value to lane 0
    }
    if (DOACT) { if (ss == t && (t > 0 || W1)) Otf = -recvH; }  // adopt scale

    const float up0   = __builtin_amdgcn_exp2f(fminf(recvH + Otf, 80.0f));
    const float diag0 = diagHold;          // 2^16 * F[row ib][j-1], stored dom.
    diagHold = up0 * 65536.0f;             // 2^16 * F[row ib][j] for next step

    const int j = ss - t + 1;
    const uint2 c = ring[u];

    // refill slot u for step ss+RING from the LDS ring (ds_read_b64)
    ring[u] = P[(ss + RING) & 127][t];

    bool act = true;
    if (DOGUARD) act = (j >= 1) && (j <= NN);
    if (act) {
        float dd[4];                       // bf16 -> f32: shl/and, exact
        dd[0] = __uint_as_float(c.x << 16);
        dd[1] = __uint_as_float(c.x & 0xFFFF0000u);
        dd[2] = __uint_as_float(c.y << 16);
        dd[3] = __uint_as_float(c.y & 0xFFFF0000u);

        float pre[4], cc[4];
        pre[0] = diag0 + L[0];
        #pragma unroll
        for (int k = 1; k < 4; ++k)
            pre[k] = fmaf(65536.0f, L[k - 1], L[k]);
        #pragma unroll
        for (int k = 0; k < 4; ++k) cc[k] = dd[k] * pre[k];
        float r = up0;
        #pragma unroll
        for (int k = 0; k < 4; ++k) {      // serial chain: 4 fma
            r = fmaf(dd[k], r, cc[k]);
            L[k] = r;
        }

        if (DOREN) {   // branchless full normalization: max(L) -> [1,2)
            float m4 = fmaxf(fmaxf(L[0], L[1]), fmaxf(L[2], L[3]));
            const int   e  = (int)(__float_as_uint(m4) >> 23) - 127;
            const float sc = __uint_as_float((unsigned)(127 - e) << 23); // 2^-e
            #pragma unroll
            for (int k = 0; k < 4; ++k) L[k] *= sc;
            diagHold *= sc;
            Otf -= (float)e;
        }

        h = __builtin_amdgcn_logf(L[3]) - Otf;   // absolute log2-domain handoff
        if (!W1) h0[j] = h;                // publish row-boundary value
    }
}

static __device__ __forceinline__ void run_chunk(
    bool W1, bool ACT, bool GUARD, int base,
    int t, const uint2 (* __restrict__ P)[64],
    uint2* ring, float* L, float& diagHold, float& h, float& Otf,
    float& hbuf, float* __restrict__ h0)
{
    for (int sb = 0; sb < 32; sb += RING)
        #pragma unroll
        for (int u = 0; u < RING; ++u)
            dtw_step4(W1, ACT, GUARD, (u & 1) == 1,
                      base + sb + u, u, t, P, ring, L,
                      diagHold, h, Otf, hbuf, h0);
}

__global__ __launch_bounds__(256) void dtw_kernel(const uint2* __restrict__ Wd,
                                                  float* __restrict__ out) {
    __shared__ __align__(16) uint2 lring[2][128][64];   // 2 x 64KB step rings
    __shared__ float h0[584];
    const int b    = blockIdx.x;
    const int tid  = threadIdx.x;
    const int t    = tid & 63;
    const int wave = tid >> 6;

    // loader wave's global plane base (flat uint4 view; 32 uint4 per step row)
    const int lp = (wave >= 2) ? (wave - 2) : 0;
    const uint4* __restrict__ gp =
        (const uint4*)(Wd + ((size_t)(b * 2 + lp) * SD) * 64);

    // pre-loop: loaders fill steps [0,64) (slots 0,1) of their plane
    if (wave >= 2) {
        uint4* l4 = (uint4*)&lring[lp][0][0];
        #pragma unroll
        for (int k = 0; k < 32; ++k)
            l4[t + 64 * k] = gp[t + 64 * k];
    }

    // DP state (dead in loader waves)
    float L[4] = {0.f, 0.f, 0.f, 0.f};     // F(boundary) = 0
    float diagHold = (wave == 0 && t == 0) ? 65536.0f : 0.0f; // 2^16*F[0][0]
    float h = NINF, Otf = 0.0f, hbuf = NINF;
    uint2 ring[RING];
    const uint2 (* __restrict__ P)[64] = lring[wave & 1];

    __syncthreads();   // initial slots visible to DP waves

    if (wave < 2) {
        #pragma unroll
        for (int u = 0; u < RING; ++u)
            ring[u] = P[u][t];             // in-reg prefill, steps 0..RING-1
    }

    for (int w = 0; w < 22; ++w) {
        if (wave == 0) {
            if (w <= 1)
                run_chunk(false, true,  true,  32*w, t, P, ring, L, diagHold, h, Otf, hbuf, h0);
            else if (w <= 15)
                run_chunk(false, false, false, 32*w, t, P, ring, L, diagHold, h, Otf, hbuf, h0);
            else if (w <= 17)
                run_chunk(false, false, true,  32*w, t, P, ring, L, diagHold, h, Otf, hbuf, h0);
        } else if (wave == 1) {
            const int c2 = w - 4;          // wave 1 lags 4 walls (128 steps)
            if (c2 >= 0) {
                if (c2 <= 1)
                    run_chunk(true, true,  true,  32*c2, t, P, ring, L, diagHold, h, Otf, hbuf, h0);
                else if (c2 <= 15)
                    run_chunk(true, false, false, 32*c2, t, P, ring, L, diagHold, h, Otf, hbuf, h0);
                else
                    run_chunk(true, false, true,  32*c2, t, P, ring, L, diagHold, h, Otf, hbuf, h0);
            }
        } else {
            // loader: fill slot for consumer's wall w+2 (plane0) / its lagged
            // equivalent (plane1, offset -2 walls)
            const int  s0 = (lp == 0) ? 32 * (w + 2) : 32 * (w - 2);
            const bool on = (lp == 0) ? (w <= 16) : (w >= 4 && w <= 20);
            if (on) {
                int nrows = 592 - s0; if (nrows > 32) nrows = 32;   // 32 or 16
                const uint4* gs = gp + (size_t)s0 * 32;
                uint4* ls = (uint4*)&lring[lp][s0 & 127][0];
                const int kn = nrows >> 1;        // uint4-chunks of 2 rows
                #pragma unroll
                for (int k = 0; k < 16; ++k)
                    if (k < kn) ls[t + 64 * k] = gs[t + 64 * k];
            }
        }
        __syncthreads();
        // preload wave 1's next 64 boundary values every other wall
        if (wave == 1 && (w & 1) && w >= 3 && w <= 19)
            hbuf = h0[(w - 3) * 32 + 1 + t];
    }

    // F[512][512] = 2^(16*1024) e^{-R}; h = log2 F (absolute)
    if (wave == 1 && t == 63) out[b] = (16384.0f - h) * LN2;
}

extern "C" void kernel_launch(void* const* d_in, const int* in_sizes, int n_in,
                              void* d_out, int out_size, void* d_ws, size_t ws_size,
                              hipStream_t stream) {
    const float* X = (const float*)d_in[0];
    const float* Y = (const float*)d_in[1];
    float* out = (float*)d_out;

    // workspace layout (ws >= 64 MB):
    //   [0, 38.8 MB)        Wd  : bf16 W, plane-major [plane<128][s<592][t<64]
    //   [40 MB, +4 MB)      Xp  : packed bf16 X fragments
    //   [44 MB, +4 MB)      Yp  : packed bf16 Y fragments
    //   [48 MB, +128 KB)    nx  : fp32 row norms of X
    //   [+128 KB, +256 KB)  ny  : fp32 row norms of Y
    char* ws = (char*)d_ws;
    uint2* Wd = (uint2*)ws;
    unsigned short* Xp = (unsigned short*)(ws + 41943040);
    unsigned short* Yp = (unsigned short*)(ws + 41943040 + 4194304);
    float* nx = (float*)(ws + 41943040 + 2 * 4194304);
    float* ny = (float*)(ws + 41943040 + 2 * 4194304 + 131072);

    pack_kernel<<<dim3(NB * NN / 256, 2), 256, 0, stream>>>(X, Y, Xp, Yp, nx, ny);
    cdist_kernel<<<dim3(4, 4, NB), 256, 0, stream>>>(Xp, Yp, nx, ny, Wd);
    dtw_kernel<<<NB, 256, 0, stream>>>(Wd, out);
}

// Round 4
// 156.167 us; speedup vs baseline: 1.2261x; 1.2261x over previous
//
#include <hip/hip_runtime.h>
#include <math.h>

// Problem constants: B=64, N=512, d=64
#define NB 64
#define NN 512
#define ND 64

#define LOG2E 1.4426950408889634f
#define LN2   0.6931471805599453f
#define RING  16                      // prefetch ring depth (columns in flight)
#define EMIN  (-100000000)            // integer-exponent encoding of value 0
#define NINF  __int_as_float(0xFF800000u)   // -inf

typedef __attribute__((ext_vector_type(8))) short  bf16x8;  // 8 bf16 in 4 VGPRs
typedef __attribute__((ext_vector_type(4))) float  f32x4;

// fp32 -> bf16 bits, round-to-nearest-even (inputs are finite)
static __device__ __forceinline__ unsigned short f2bf(float f) {
    unsigned u = __float_as_uint(f);
    u += 0x7FFFu + ((u >> 16) & 1u);
    return (unsigned short)(u >> 16);
}

// ---------------------------------------------------------------------------
// Kernel 0 (pack): X,Y (f32 row-major) -> bf16 in MFMA-fragment order, plus
// fp32 row norms (R12/R13-proven, unchanged).
// ---------------------------------------------------------------------------
__global__ __launch_bounds__(256) void pack_kernel(const float* __restrict__ X,
                                                   const float* __restrict__ Y,
                                                   unsigned short* __restrict__ Xp,
                                                   unsigned short* __restrict__ Yp,
                                                   float* __restrict__ nx,
                                                   float* __restrict__ ny) {
    const int gid = blockIdx.x * 256 + threadIdx.x;   // row id, 0..NB*NN-1
    const float* src;
    unsigned short* dst;
    float* ndst;
    if (blockIdx.y == 0) { src = X + (size_t)gid * ND; dst = Xp; ndst = nx; }
    else                 { src = Y + (size_t)gid * ND; dst = Yp; ndst = ny; }

    float v[ND];
    float s = 0.f;
    #pragma unroll
    for (int k = 0; k < ND; k += 4) {
        float4 f = *(const float4*)(src + k);
        v[k] = f.x; v[k + 1] = f.y; v[k + 2] = f.z; v[k + 3] = f.w;
        s += f.x * f.x + f.y * f.y + f.z * f.z + f.w * f.w;
    }
    ndst[gid] = s;

    const int b  = gid >> 9;
    const int i  = gid & 511;
    const int it = i >> 4;             // 16-row tile
    const int lm = i & 15;             // row within tile
    #pragma unroll
    for (int h = 0; h < 2; ++h) {
        #pragma unroll
        for (int q = 0; q < 4; ++q) {
            unsigned w[4];
            #pragma unroll
            for (int m = 0; m < 4; ++m) {
                const int c = h * 32 + q * 8 + 2 * m;
                w[m] = (unsigned)f2bf(v[c]) | ((unsigned)f2bf(v[c + 1]) << 16);
            }
            uint4 pkt; pkt.x = w[0]; pkt.y = w[1]; pkt.z = w[2]; pkt.w = w[3];
            *(uint4*)(dst + ((((size_t)b * 32 + it) * 2 + h) << 9)
                          + (size_t)(q * 16 + lm) * 8) = pkt;
        }
    }
}

// ---------------------------------------------------------------------------
// Kernel 1 (MFMA): Wt[b][i][j] = bf16( exp2(16 - log2e*||X[b][i]-Y[b][j]||) )
// (R13-proven, byte-identical to the 145.7us R0 version.)
// ---------------------------------------------------------------------------
__global__ __launch_bounds__(256) void cdist_kernel(const unsigned short* __restrict__ Xp,
                                                    const unsigned short* __restrict__ Yp,
                                                    const float* __restrict__ nx,
                                                    const float* __restrict__ ny,
                                                    unsigned short* __restrict__ Wt) {
    const int b  = blockIdx.z;
    const int ib = blockIdx.x * 128;   // i base (X rows)
    const int jb = blockIdx.y * 128;   // j base (Y rows)
    const int t  = threadIdx.x;

    const int wave = t >> 6;
    const int wi   = (wave & 1) * 64;   // i offset of this wave's 64x64 tile
    const int wj   = (wave >> 1) * 64;  // j offset
    const int lane = t & 63;
    const int lm   = lane & 15;
    const int quad = lane >> 4;

    f32x4 acc[4][4];
    #pragma unroll
    for (int mt = 0; mt < 4; ++mt)
        #pragma unroll
        for (int nt = 0; nt < 4; ++nt)
            acc[mt][nt] = (f32x4){0.f, 0.f, 0.f, 0.f};

    const int jt0 = (jb + wj) >> 4;    // Y tile base
    const int it0 = (ib + wi) >> 4;    // X tile base

    #pragma unroll
    for (int h = 0; h < 2; ++h) {
        bf16x8 Af[4], Bf[4];
        #pragma unroll
        for (int mt = 0; mt < 4; ++mt)   // A from Y tiles (m = j dim)
            Af[mt] = *(const bf16x8*)(Yp
                + ((((size_t)b * 32 + jt0 + mt) * 2 + h) << 9) + (size_t)lane * 8);
        #pragma unroll
        for (int nt = 0; nt < 4; ++nt)   // B from X tiles (n = i dim)
            Bf[nt] = *(const bf16x8*)(Xp
                + ((((size_t)b * 32 + it0 + nt) * 2 + h) << 9) + (size_t)lane * 8);
        #pragma unroll
        for (int mt = 0; mt < 4; ++mt)
            #pragma unroll
            for (int nt = 0; nt < 4; ++nt)
                acc[mt][nt] = __builtin_amdgcn_mfma_f32_16x16x32_bf16(
                    Af[mt], Bf[nt], acc[mt][nt], 0, 0, 0);
    }

    float nxv[4];
    float4 nyv[4];
    #pragma unroll
    for (int nt = 0; nt < 4; ++nt)
        nxv[nt] = nx[(size_t)b * NN + ib + wi + nt * 16 + lm];
    #pragma unroll
    for (int mt = 0; mt < 4; ++mt)
        nyv[mt] = *(const float4*)(ny + (size_t)b * NN + jb + wj + mt * 16 + quad * 4);

    #pragma unroll
    for (int nt = 0; nt < 4; ++nt) {
        const int i = ib + wi + nt * 16 + lm;
        unsigned short* Drow = Wt + ((size_t)b * NN + i) * NN + jb + wj;
        #pragma unroll
        for (int mt = 0; mt < 4; ++mt) {
            const float* nyp = (const float*)&nyv[mt];
            unsigned a[4];
            #pragma unroll
            for (int r = 0; r < 4; ++r) {
                float d2 = nyp[r] + nxv[nt] - 2.0f * acc[mt][nt][r];
                float w  = __builtin_amdgcn_exp2f(16.0f - LOG2E * sqrtf(fmaxf(d2, 0.f)));
                a[r] = __float_as_uint(w) + 0x8000u;   // round-half-up to bf16
            }
            uint2 pkt;
            pkt.x = (a[0] >> 16) | (a[1] & 0xFFFF0000u);
            pkt.y = (a[2] >> 16) | (a[3] & 0xFFFF0000u);
            *(uint2*)(Drow + mt * 16 + quad * 4) = pkt;
        }
    }
}

// ---------------------------------------------------------------------------
// Kernel 2: soft-DTW DP. R17: structure, memory path, walls, ring = exact R0
// (the 145.7us version). ONLY the cross-lane handoff changed: instead of
// h = log2(L[3]) - Otf  (v_log on produce, v_exp on consume -- two
// quarter-rate transcendentals on the serial zigzag chain every step), the
// handoff is the EXACT pair (m, E): m = mantissa(L[3]) in [1,2),
// E = expfield(L[3]) - 127 - Otf (absolute int exponent). Consumer rebuilds
// up0 = m * 2^(E + Otf_local) by integer exponent surgery (add/shift/
// cndmask). Otf becomes an integer frame. Value 0 encoded as E = EMIN.
// Removes both transcendentals from the recurrence (and is exact, so it
// also removes 512+ exp(log(x)) roundtrip errors). One v_log remains, at
// the very end, for the output.
// ---------------------------------------------------------------------------
static __device__ __forceinline__ float dpp_shr1(float x, float old) {
    return __int_as_float(__builtin_amdgcn_update_dpp(
        __float_as_int(old), __float_as_int(x), 0x138, 0xf, 0xf, false));
}
static __device__ __forceinline__ float dpp_shl1(float x) {
    return __int_as_float(__builtin_amdgcn_update_dpp(
        0, __float_as_int(x), 0x130, 0xf, 0xf, false));
}
static __device__ __forceinline__ int dpp_shr1_i(int x, int old) {
    return __builtin_amdgcn_update_dpp(old, x, 0x138, 0xf, 0xf, false);
}
static __device__ __forceinline__ int dpp_shl1_i(int x) {
    return __builtin_amdgcn_update_dpp(0, x, 0x130, 0xf, 0xf, false);
}

static __device__ __forceinline__ void dtw_step4(
    bool W1, bool DOACT, bool DOGUARD, bool DOCLAMP, bool DOREN,
    int ss, int u, int t, const unsigned short* __restrict__ Wb, int ib,
    uint2* ring, float* L, float& diagHold, float& hm, int& he, int& Otf,
    float& hbufM, int& hbufE, float* __restrict__ h0m, int* __restrict__ h0e)
{
    // intra-wave handoff: lane t gets lane t-1's (m,E) (lane 0: zero-value)
    float recvM = dpp_shr1(hm, 0.0f);
    int   recvE = dpp_shr1_i(he, EMIN);
    if (W1) {
        recvM = (t == 0) ? hbufM : recvM;  // lane 0: cross-wave value from LDS
        recvE = (t == 0) ? hbufE : recvE;
        hbufM = dpp_shl1(hbufM);           // rotate: next step's value to lane 0
        hbufE = dpp_shl1_i(hbufE);
    }
    if (DOACT) { if (ss == t && (t > 0 || W1)) Otf = -recvE; }  // adopt frame

    // up0 = recvM * 2^(recvE + Otf), exact, no transcendental
    int k  = recvE + Otf;
    k      = k > 80 ? 80 : k;              // cap (was fminf(...,80))
    int kb = k < -200 ? -200 : k;          // keep shift well-defined
    const float up0 = (k < -126) ? 0.0f
        : __int_as_float(__float_as_int(recvM) + (kb << 23));

    const float diag0 = diagHold;          // 2^16 * F[row ib][j-1], stored dom.
    diagHold = up0 * 65536.0f;             // 2^16 * F[row ib][j] for next step

    const int j = ss - t + 1;
    const uint2 c = ring[u];

    // refill slot u for step ss+RING (unconditional; overrun reads dead data)
    {
        int jn = j + RING;
        if (DOCLAMP) jn = jn < 1 ? 1 : jn;
        ring[u] = *(const uint2*)(Wb + (size_t)(jn - 1) * NN + ib);
    }

    bool act = true;
    if (DOGUARD) act = (j >= 1) && (j <= NN);
    if (act) {
        float dd[4];                       // bf16 -> f32: shl/and, exact
        dd[0] = __uint_as_float(c.x << 16);
        dd[1] = __uint_as_float(c.x & 0xFFFF0000u);
        dd[2] = __uint_as_float(c.y << 16);
        dd[3] = __uint_as_float(c.y & 0xFFFF0000u);

        float pre[4], cc[4];
        pre[0] = diag0 + L[0];
        #pragma unroll
        for (int kk = 1; kk < 4; ++kk)
            pre[kk] = fmaf(65536.0f, L[kk - 1], L[kk]);
        #pragma unroll
        for (int kk = 0; kk < 4; ++kk) cc[kk] = dd[kk] * pre[kk];
        float r = up0;
        #pragma unroll
        for (int kk = 0; kk < 4; ++kk) {   // serial chain: 4 fma
            r = fmaf(dd[kk], r, cc[kk]);
            L[kk] = r;
        }

        if (DOREN) {   // branchless full normalization: max(L) -> [1,2)
            float m4 = fmaxf(fmaxf(L[0], L[1]), fmaxf(L[2], L[3]));
            const int   e  = (int)(__float_as_uint(m4) >> 23) - 127;
            const float sc = __uint_as_float((unsigned)(127 - e) << 23); // 2^-e
            #pragma unroll
            for (int kk = 0; kk < 4; ++kk) L[kk] *= sc;
            diagHold *= sc;
            Otf -= e;
        }

        // handoff pair from L[3]: exact mantissa/exponent split
        const int lb = __float_as_int(L[3]);
        const int le = (lb >> 23) & 0xFF;               // biased exponent
        const float mm = __int_as_float((lb & 0x007FFFFF) | 0x3F800000);
        const bool  z  = (le == 0);                     // L[3] == 0 / denorm
        hm = z ? 0.0f : mm;
        he = z ? EMIN : (le - 127 - Otf);               // absolute exponent
        if (!W1) { h0m[j] = hm; h0e[j] = he; }          // publish boundary
    }
}

static __device__ __forceinline__ void run_chunk(
    bool W1, bool ACT, bool GUARD, bool CLAMP, int base,
    int t, const unsigned short* __restrict__ Wb, int ib,
    uint2* ring, float* L, float& diagHold, float& hm, int& he, int& Otf,
    float& hbufM, int& hbufE, float* __restrict__ h0m, int* __restrict__ h0e)
{
    for (int sb = 0; sb < 64; sb += RING)
        #pragma unroll
        for (int u = 0; u < RING; ++u)
            dtw_step4(W1, ACT, GUARD, CLAMP, (u & 1) == 1,
                      base + sb + u, u, t, Wb, ib, ring, L,
                      diagHold, hm, he, Otf, hbufM, hbufE, h0m, h0e);
}

__global__ __launch_bounds__(128) void dtw_kernel(const unsigned short* __restrict__ Wt,
                                                  float* __restrict__ out) {
    __shared__ float h0m[584];
    __shared__ int   h0e[584];
    const int b    = blockIdx.x;
    const int tid  = threadIdx.x;
    const int t    = tid & 63;
    const int wave = tid >> 6;
    const unsigned short* __restrict__ Wb = Wt + (size_t)b * NN * NN;
    const int ib = wave * 256 + 4 * t;     // first owned row - 1

    float L[4] = {0.f, 0.f, 0.f, 0.f};     // F(boundary) = 0
    float diagHold = (wave == 0 && t == 0) ? 65536.0f : 0.0f; // 2^16*F[0][0]
    float hm = 0.0f, hbufM = 0.0f;
    int   he = EMIN, hbufE = EMIN, Otf = 0;

    uint2 ring[RING];
    #pragma unroll
    for (int u = 0; u < RING; ++u) {
        int col = u - t + 1;
        col = col < 1 ? 1 : col;           // clamp; dead if OOB
        ring[u] = *(const uint2*)(Wb + (size_t)(col - 1) * NN + ib);
    }

    for (int wall = 0; wall < 11; ++wall) {
        const int ch = wave ? wall - 2 : wall;   // wave 1 lags 2 chunks
        if (wave == 0) {
            if (ch == 0)
                run_chunk(false, true,  true,  true,  0,      t, Wb, ib, ring, L, diagHold, hm, he, Otf, hbufM, hbufE, h0m, h0e);
            else if (ch >= 1 && ch <= 7)
                run_chunk(false, false, false, false, ch*64,  t, Wb, ib, ring, L, diagHold, hm, he, Otf, hbufM, hbufE, h0m, h0e);
            else if (ch == 8)
                run_chunk(false, false, true,  false, 512,    t, Wb, ib, ring, L, diagHold, hm, he, Otf, hbufM, hbufE, h0m, h0e);
        } else {
            if (ch == 0)
                run_chunk(true,  true,  true,  true,  0,      t, Wb, ib, ring, L, diagHold, hm, he, Otf, hbufM, hbufE, h0m, h0e);
            else if (ch >= 1 && ch <= 7)
                run_chunk(true,  false, false, false, ch*64,  t, Wb, ib, ring, L, diagHold, hm, he, Otf, hbufM, hbufE, h0m, h0e);
            else if (ch == 8)
                run_chunk(true,  false, true,  false, 512,    t, Wb, ib, ring, L, diagHold, hm, he, Otf, hbufM, hbufE, h0m, h0e);
        }
        __syncthreads();
        // preload wave 1's next-chunk boundary values (cols base+1..base+64)
        if (wave && wall >= 1 && wall <= 9) {
            hbufM = h0m[(wall - 1) * 64 + 1 + t];
            hbufE = h0e[(wall - 1) * 64 + 1 + t];
        }
    }

    // F[512][512] = 2^(16*1024) e^{-R}; log2 F = log2(hm) + he (absolute)
    if (wave == 1 && t == 63)
        out[b] = (16384.0f - (__builtin_amdgcn_logf(hm) + (float)he)) * LN2;
}

extern "C" void kernel_launch(void* const* d_in, const int* in_sizes, int n_in,
                              void* d_out, int out_size, void* d_ws, size_t ws_size,
                              hipStream_t stream) {
    const float* X = (const float*)d_in[0];
    const float* Y = (const float*)d_in[1];
    float* out = (float*)d_out;

    // workspace layout (ws >= 64 MB):
    //   [0, 32 MB)      Wt  : bf16 W matrix, layout [b][i][j]
    //   [32, 36 MB)     Xp  : packed bf16 X fragments
    //   [36, 40 MB)     Yp  : packed bf16 Y fragments
    //   [40 MB, +128KB) nx  : fp32 row norms of X
    //   [+128KB,+256KB) ny  : fp32 row norms of Y
    char* ws = (char*)d_ws;
    unsigned short* Wt = (unsigned short*)(ws);
    unsigned short* Xp = (unsigned short*)(ws + (33554432));
    unsigned short* Yp = (unsigned short*)(ws + (33554432 + 4194304));
    float* nx = (float*)(ws + (33554432 + 2 * 4194304));
    float* ny = (float*)(ws + (33554432 + 2 * 4194304 + 131072));

    pack_kernel<<<dim3(NB * NN / 256, 2), 256, 0, stream>>>(X, Y, Xp, Yp, nx, ny);
    cdist_kernel<<<dim3(4, 4, NB), 256, 0, stream>>>(Xp, Yp, nx, ny, Wt);
    dtw_kernel<<<NB, 128, 0, stream>>>(Wt, out);
}

// Round 5
// 146.613 us; speedup vs baseline: 1.3060x; 1.0652x over previous
//
#include <hip/hip_runtime.h>
#include <math.h>

// Problem constants: B=64, N=512, d=64
#define NB 64
#define NN 512
#define ND 64

#define LOG2E 1.4426950408889634f
#define LN2   0.6931471805599453f
#define RING  16                      // prefetch ring depth (columns in flight)
#define NINF  __int_as_float(0xFF800000u)   // -inf

typedef __attribute__((ext_vector_type(8))) short  bf16x8;  // 8 bf16 in 4 VGPRs
typedef __attribute__((ext_vector_type(4))) float  f32x4;

// fp32 -> bf16 bits, round-to-nearest-even (inputs are finite)
static __device__ __forceinline__ unsigned short f2bf(float f) {
    unsigned u = __float_as_uint(f);
    u += 0x7FFFu + ((u >> 16) & 1u);
    return (unsigned short)(u >> 16);
}

// ---------------------------------------------------------------------------
// Kernel 0 (pack): X,Y (f32 row-major) -> bf16 in MFMA-fragment order, plus
// fp32 row norms (R12/R13-proven, unchanged).
// ---------------------------------------------------------------------------
__global__ __launch_bounds__(256) void pack_kernel(const float* __restrict__ X,
                                                   const float* __restrict__ Y,
                                                   unsigned short* __restrict__ Xp,
                                                   unsigned short* __restrict__ Yp,
                                                   float* __restrict__ nx,
                                                   float* __restrict__ ny) {
    const int gid = blockIdx.x * 256 + threadIdx.x;   // row id, 0..NB*NN-1
    const float* src;
    unsigned short* dst;
    float* ndst;
    if (blockIdx.y == 0) { src = X + (size_t)gid * ND; dst = Xp; ndst = nx; }
    else                 { src = Y + (size_t)gid * ND; dst = Yp; ndst = ny; }

    float v[ND];
    float s = 0.f;
    #pragma unroll
    for (int k = 0; k < ND; k += 4) {
        float4 f = *(const float4*)(src + k);
        v[k] = f.x; v[k + 1] = f.y; v[k + 2] = f.z; v[k + 3] = f.w;
        s += f.x * f.x + f.y * f.y + f.z * f.z + f.w * f.w;
    }
    ndst[gid] = s;

    const int b  = gid >> 9;
    const int i  = gid & 511;
    const int it = i >> 4;             // 16-row tile
    const int lm = i & 15;             // row within tile
    #pragma unroll
    for (int h = 0; h < 2; ++h) {
        #pragma unroll
        for (int q = 0; q < 4; ++q) {
            unsigned w[4];
            #pragma unroll
            for (int m = 0; m < 4; ++m) {
                const int c = h * 32 + q * 8 + 2 * m;
                w[m] = (unsigned)f2bf(v[c]) | ((unsigned)f2bf(v[c + 1]) << 16);
            }
            uint4 pkt; pkt.x = w[0]; pkt.y = w[1]; pkt.z = w[2]; pkt.w = w[3];
            *(uint4*)(dst + ((((size_t)b * 32 + it) * 2 + h) << 9)
                          + (size_t)(q * 16 + lm) * 8) = pkt;
        }
    }
}

// ---------------------------------------------------------------------------
// Kernel 1 (MFMA): Wt[b][i][j] = bf16( exp2(16 - log2e*||X[b][i]-Y[b][j]||) )
// R18: same math and same [b][i][j] output layout as the proven R0 version,
// but the epilogue stages the 128x128 tile in LDS and writes out fully-
// coalesced, full-cache-line uint4 stores (4 rows x 256B per wave per
// instruction). The old direct fragment stores were 16 partial-line 32B
// pieces at exact 1KB power-of-2 stride per instruction -- L2 bank/channel
// aliasing + partial-line merge traffic (~29us slower than scatter stores
// across R0..R2 cross-round evidence). Values are bit-identical (rounding
// happens before staging), so dtw input is unchanged.
// ---------------------------------------------------------------------------
__global__ __launch_bounds__(256) void cdist_kernel(const unsigned short* __restrict__ Xp,
                                                    const unsigned short* __restrict__ Yp,
                                                    const float* __restrict__ nx,
                                                    const float* __restrict__ ny,
                                                    unsigned short* __restrict__ Wt) {
    // 128x128 bf16 tile, row stride 136 shorts (272B = 17x16B: keeps rows
    // 16B-aligned; 68 dwords/row spreads banks by 4/row).
    __shared__ unsigned short tile[128][136];

    const int b  = blockIdx.z;
    const int ib = blockIdx.x * 128;   // i base (X rows)
    const int jb = blockIdx.y * 128;   // j base (Y rows)
    const int t  = threadIdx.x;

    const int wave = t >> 6;
    const int wi   = (wave & 1) * 64;   // i offset of this wave's 64x64 tile
    const int wj   = (wave >> 1) * 64;  // j offset
    const int lane = t & 63;
    const int lm   = lane & 15;
    const int quad = lane >> 4;

    f32x4 acc[4][4];
    #pragma unroll
    for (int mt = 0; mt < 4; ++mt)
        #pragma unroll
        for (int nt = 0; nt < 4; ++nt)
            acc[mt][nt] = (f32x4){0.f, 0.f, 0.f, 0.f};

    const int jt0 = (jb + wj) >> 4;    // Y tile base
    const int it0 = (ib + wi) >> 4;    // X tile base

    #pragma unroll
    for (int h = 0; h < 2; ++h) {
        bf16x8 Af[4], Bf[4];
        #pragma unroll
        for (int mt = 0; mt < 4; ++mt)   // A from Y tiles (m = j dim)
            Af[mt] = *(const bf16x8*)(Yp
                + ((((size_t)b * 32 + jt0 + mt) * 2 + h) << 9) + (size_t)lane * 8);
        #pragma unroll
        for (int nt = 0; nt < 4; ++nt)   // B from X tiles (n = i dim)
            Bf[nt] = *(const bf16x8*)(Xp
                + ((((size_t)b * 32 + it0 + nt) * 2 + h) << 9) + (size_t)lane * 8);
        #pragma unroll
        for (int mt = 0; mt < 4; ++mt)
            #pragma unroll
            for (int nt = 0; nt < 4; ++nt)
                acc[mt][nt] = __builtin_amdgcn_mfma_f32_16x16x32_bf16(
                    Af[mt], Bf[nt], acc[mt][nt], 0, 0, 0);
    }

    float nxv[4];
    float4 nyv[4];
    #pragma unroll
    for (int nt = 0; nt < 4; ++nt)
        nxv[nt] = nx[(size_t)b * NN + ib + wi + nt * 16 + lm];
    #pragma unroll
    for (int mt = 0; mt < 4; ++mt)
        nyv[mt] = *(const float4*)(ny + (size_t)b * NN + jb + wj + mt * 16 + quad * 4);

    // fragments -> LDS (math bit-identical to R0's direct-store version)
    #pragma unroll
    for (int nt = 0; nt < 4; ++nt) {
        const int ri = wi + nt * 16 + lm;          // local i row
        #pragma unroll
        for (int mt = 0; mt < 4; ++mt) {
            const float* nyp = (const float*)&nyv[mt];
            unsigned a[4];
            #pragma unroll
            for (int r = 0; r < 4; ++r) {
                float d2 = nyp[r] + nxv[nt] - 2.0f * acc[mt][nt][r];
                float w  = __builtin_amdgcn_exp2f(16.0f - LOG2E * sqrtf(fmaxf(d2, 0.f)));
                a[r] = __float_as_uint(w) + 0x8000u;   // round-half-up to bf16
            }
            uint2 pkt;
            pkt.x = (a[0] >> 16) | (a[1] & 0xFFFF0000u);
            pkt.y = (a[2] >> 16) | (a[3] & 0xFFFF0000u);
            *(uint2*)&tile[ri][wj + mt * 16 + quad * 4] = pkt;
        }
    }
    __syncthreads();

    // coalesced write-out: 8 rounds, each wave stores 4 rows x 256B of full
    // aligned 64B lines (uint4 per lane).
    const int rrb = t >> 4;            // 0..15: row-within-group
    const int cc  = (t & 15) * 8;      // short offset within row (16B/lane)
    #pragma unroll
    for (int round = 0; round < 8; ++round) {
        const int rr = round * 16 + rrb;
        uint4 v = *(const uint4*)&tile[rr][cc];
        *(uint4*)(Wt + ((size_t)b * NN + ib + rr) * NN + jb + cc) = v;
    }
}

// ---------------------------------------------------------------------------
// Kernel 2: soft-DTW DP, exp-domain chain -- EXACT R0 code (the proven 65us
// version; R14-R17 alternatives all regressed). Two pipelined waves per
// batch, 4 rows/lane, log2-domain absolute handoff h via DPP + LDS.
// ---------------------------------------------------------------------------
static __device__ __forceinline__ float dpp_shr1(float x, float old) {
    return __int_as_float(__builtin_amdgcn_update_dpp(
        __float_as_int(old), __float_as_int(x), 0x138, 0xf, 0xf, false));
}
static __device__ __forceinline__ float dpp_shl1(float x) {
    return __int_as_float(__builtin_amdgcn_update_dpp(
        0, __float_as_int(x), 0x130, 0xf, 0xf, false));
}

static __device__ __forceinline__ void dtw_step4(
    bool W1, bool DOACT, bool DOGUARD, bool DOCLAMP, bool DOREN,
    int ss, int u, int t, const unsigned short* __restrict__ Wb, int ib,
    uint2* ring, float* L, float& diagHold, float& h, float& Otf,
    float& hbuf, float* __restrict__ h0)
{
    // intra-wave handoff: lane t gets lane t-1's h (lane 0: -inf)
    float recvH = dpp_shr1(h, NINF);
    if (W1) {
        recvH = (t == 0) ? hbuf : recvH;   // lane 0: cross-wave value from LDS
        hbuf  = dpp_shl1(hbuf);            // rotate: next step's value to lane 0
    }
    if (DOACT) { if (ss == t && (t > 0 || W1)) Otf = -recvH; }  // adopt scale

    const float up0   = __builtin_amdgcn_exp2f(fminf(recvH + Otf, 80.0f));
    const float diag0 = diagHold;          // 2^16 * F[row ib][j-1], stored dom.
    diagHold = up0 * 65536.0f;             // 2^16 * F[row ib][j] for next step

    const int j = ss - t + 1;
    const uint2 c = ring[u];

    // refill slot u for step ss+RING (unconditional; overrun reads dead data)
    {
        int jn = j + RING;
        if (DOCLAMP) jn = jn < 1 ? 1 : jn;
        ring[u] = *(const uint2*)(Wb + (size_t)(jn - 1) * NN + ib);
    }

    bool act = true;
    if (DOGUARD) act = (j >= 1) && (j <= NN);
    if (act) {
        float dd[4];                       // bf16 -> f32: shl/and, exact
        dd[0] = __uint_as_float(c.x << 16);
        dd[1] = __uint_as_float(c.x & 0xFFFF0000u);
        dd[2] = __uint_as_float(c.y << 16);
        dd[3] = __uint_as_float(c.y & 0xFFFF0000u);

        float pre[4], cc[4];
        pre[0] = diag0 + L[0];
        #pragma unroll
        for (int k = 1; k < 4; ++k)
            pre[k] = fmaf(65536.0f, L[k - 1], L[k]);
        #pragma unroll
        for (int k = 0; k < 4; ++k) cc[k] = dd[k] * pre[k];
        float r = up0;
        #pragma unroll
        for (int k = 0; k < 4; ++k) {      // serial chain: 4 fma
            r = fmaf(dd[k], r, cc[k]);
            L[k] = r;
        }

        if (DOREN) {   // branchless full normalization: max(L) -> [1,2)
            float m4 = fmaxf(fmaxf(L[0], L[1]), fmaxf(L[2], L[3]));
            const int   e  = (int)(__float_as_uint(m4) >> 23) - 127;
            const float sc = __uint_as_float((unsigned)(127 - e) << 23); // 2^-e
            #pragma unroll
            for (int k = 0; k < 4; ++k) L[k] *= sc;
            diagHold *= sc;
            Otf -= (float)e;
        }

        h = __builtin_amdgcn_logf(L[3]) - Otf;   // absolute log2-domain handoff
        if (!W1) h0[j] = h;                // publish row-boundary value
    }
}

static __device__ __forceinline__ void run_chunk(
    bool W1, bool ACT, bool GUARD, bool CLAMP, int base,
    int t, const unsigned short* __restrict__ Wb, int ib,
    uint2* ring, float* L, float& diagHold, float& h, float& Otf,
    float& hbuf, float* __restrict__ h0)
{
    for (int sb = 0; sb < 64; sb += RING)
        #pragma unroll
        for (int u = 0; u < RING; ++u)
            dtw_step4(W1, ACT, GUARD, CLAMP, (u & 1) == 1,
                      base + sb + u, u, t, Wb, ib, ring, L,
                      diagHold, h, Otf, hbuf, h0);
}

__global__ __launch_bounds__(128) void dtw_kernel(const unsigned short* __restrict__ Wt,
                                                  float* __restrict__ out) {
    __shared__ float h0[584];
    const int b    = blockIdx.x;
    const int tid  = threadIdx.x;
    const int t    = tid & 63;
    const int wave = tid >> 6;
    const unsigned short* __restrict__ Wb = Wt + (size_t)b * NN * NN;
    const int ib = wave * 256 + 4 * t;     // first owned row - 1

    float L[4] = {0.f, 0.f, 0.f, 0.f};     // F(boundary) = 0
    float diagHold = (wave == 0 && t == 0) ? 65536.0f : 0.0f; // 2^16*F[0][0]
    float h = NINF, Otf = 0.0f, hbuf = NINF;

    uint2 ring[RING];
    #pragma unroll
    for (int u = 0; u < RING; ++u) {
        int col = u - t + 1;
        col = col < 1 ? 1 : col;           // clamp; dead if OOB
        ring[u] = *(const uint2*)(Wb + (size_t)(col - 1) * NN + ib);
    }

    for (int wall = 0; wall < 11; ++wall) {
        const int ch = wave ? wall - 2 : wall;   // wave 1 lags 2 chunks
        if (wave == 0) {
            if (ch == 0)
                run_chunk(false, true,  true,  true,  0,      t, Wb, ib, ring, L, diagHold, h, Otf, hbuf, h0);
            else if (ch >= 1 && ch <= 7)
                run_chunk(false, false, false, false, ch*64,  t, Wb, ib, ring, L, diagHold, h, Otf, hbuf, h0);
            else if (ch == 8)
                run_chunk(false, false, true,  false, 512,    t, Wb, ib, ring, L, diagHold, h, Otf, hbuf, h0);
        } else {
            if (ch == 0)
                run_chunk(true,  true,  true,  true,  0,      t, Wb, ib, ring, L, diagHold, h, Otf, hbuf, h0);
            else if (ch >= 1 && ch <= 7)
                run_chunk(true,  false, false, false, ch*64,  t, Wb, ib, ring, L, diagHold, h, Otf, hbuf, h0);
            else if (ch == 8)
                run_chunk(true,  false, true,  false, 512,    t, Wb, ib, ring, L, diagHold, h, Otf, hbuf, h0);
        }
        __syncthreads();
        // preload wave 1's next-chunk boundary values (cols base+1..base+64)
        if (wave && wall >= 1 && wall <= 9)
            hbuf = h0[(wall - 1) * 64 + 1 + t];
    }

    // F[512][512] = 2^(16*1024) e^{-R}; h = log2 F (absolute)
    if (wave == 1 && t == 63) out[b] = (16384.0f - h) * LN2;
}

extern "C" void kernel_launch(void* const* d_in, const int* in_sizes, int n_in,
                              void* d_out, int out_size, void* d_ws, size_t ws_size,
                              hipStream_t stream) {
    const float* X = (const float*)d_in[0];
    const float* Y = (const float*)d_in[1];
    float* out = (float*)d_out;

    // workspace layout (ws >= 64 MB):
    //   [0, 32 MB)      Wt  : bf16 W matrix, layout [b][i][j]
    //   [32, 36 MB)     Xp  : packed bf16 X fragments
    //   [36, 40 MB)     Yp  : packed bf16 Y fragments
    //   [40 MB, +128KB) nx  : fp32 row norms of X
    //   [+128KB,+256KB) ny  : fp32 row norms of Y
    char* ws = (char*)d_ws;
    unsigned short* Wt = (unsigned short*)(ws);
    unsigned short* Xp = (unsigned short*)(ws + (33554432));
    unsigned short* Yp = (unsigned short*)(ws + (33554432 + 4194304));
    float* nx = (float*)(ws + (33554432 + 2 * 4194304));
    float* ny = (float*)(ws + (33554432 + 2 * 4194304 + 131072));

    pack_kernel<<<dim3(NB * NN / 256, 2), 256, 0, stream>>>(X, Y, Xp, Yp, nx, ny);
    cdist_kernel<<<dim3(4, 4, NB), 256, 0, stream>>>(Xp, Yp, nx, ny, Wt);
    dtw_kernel<<<NB, 128, 0, stream>>>(Wt, out);
}

// Round 6
// 145.798 us; speedup vs baseline: 1.3133x; 1.0056x over previous
//
#include <hip/hip_runtime.h>
#include <math.h>

// Problem constants: B=64, N=512, d=64
#define NB 64
#define NN 512
#define ND 64

#define LOG2E 1.4426950408889634f
#define LN2   0.6931471805599453f
#define RING  16                      // prefetch ring depth (columns in flight)
#define NINF  __int_as_float(0xFF800000u)   // -inf

typedef __attribute__((ext_vector_type(8))) short  bf16x8;  // 8 bf16 in 4 VGPRs
typedef __attribute__((ext_vector_type(4))) float  f32x4;

// fp32 -> bf16 bits, round-to-nearest-even (inputs are finite)
static __device__ __forceinline__ unsigned short f2bf(float f) {
    unsigned u = __float_as_uint(f);
    u += 0x7FFFu + ((u >> 16) & 1u);
    return (unsigned short)(u >> 16);
}

// ---------------------------------------------------------------------------
// Kernel 1 (fused pack+MFMA):
//   Wt[b][i][j] = bf16( exp2(16 - log2e*||X[b][i]-Y[b][j]||) )
// R19: pack_kernel is FUSED in. Phase 1: each of the 256 threads reads one
// X/Y row (identical float4 sequence and summation order as the old pack ->
// bit-identical norms), converts with the same f2bf (-> bit-identical
// fragments), staging fragments+norms in LDS (33KB). Phase 2 is the proven
// R0 cdist body with LDS reads replacing global Xp/Yp/nx/ny, and the
// R0 direct uint2 stores (R18 showed staged stores are equivalent).
// Wt output is bit-identical to all prior rounds -> dtw input unchanged.
// ---------------------------------------------------------------------------
__global__ __launch_bounds__(256) void cdist_kernel(const float* __restrict__ X,
                                                    const float* __restrict__ Y,
                                                    unsigned short* __restrict__ Wt) {
    __shared__ unsigned short lX[8][2][512];   // X fragments, pack layout
    __shared__ unsigned short lY[8][2][512];   // Y fragments, pack layout
    __shared__ float nrmX[128], nrmY[128];

    const int b  = blockIdx.z;
    const int ib = blockIdx.x * 128;   // i base (X rows)
    const int jb = blockIdx.y * 128;   // j base (Y rows)
    const int t  = threadIdx.x;

    // ---- phase 1: pack this block's 128 X rows + 128 Y rows ----
    {
        const int r = t & 127;
        const float* src = (t < 128) ? X + ((size_t)b * NN + ib + r) * ND
                                     : Y + ((size_t)b * NN + jb + r) * ND;
        float v[ND];
        float s = 0.f;
        #pragma unroll
        for (int k = 0; k < ND; k += 4) {      // EXACT pack order
            float4 f = *(const float4*)(src + k);
            v[k] = f.x; v[k + 1] = f.y; v[k + 2] = f.z; v[k + 3] = f.w;
            s += f.x * f.x + f.y * f.y + f.z * f.z + f.w * f.w;
        }
        const int it = r >> 4;                 // 16-row tile
        const int lm = r & 15;                 // row within tile
        unsigned short* dst = (t < 128) ? &lX[it][0][0] : &lY[it][0][0];
        #pragma unroll
        for (int h = 0; h < 2; ++h) {
            #pragma unroll
            for (int q = 0; q < 4; ++q) {
                unsigned w[4];
                #pragma unroll
                for (int m = 0; m < 4; ++m) {
                    const int c = h * 32 + q * 8 + 2 * m;
                    w[m] = (unsigned)f2bf(v[c]) | ((unsigned)f2bf(v[c + 1]) << 16);
                }
                uint4 pkt; pkt.x = w[0]; pkt.y = w[1]; pkt.z = w[2]; pkt.w = w[3];
                *(uint4*)(dst + h * 512 + (q * 16 + lm) * 8) = pkt;
            }
        }
        if (t < 128) nrmX[r] = s; else nrmY[r] = s;
    }
    __syncthreads();

    // ---- phase 2: R0 cdist body, LDS-sourced ----
    const int wave = t >> 6;
    const int wi   = (wave & 1) * 64;   // i offset of this wave's 64x64 tile
    const int wj   = (wave >> 1) * 64;  // j offset
    const int lane = t & 63;
    const int lm   = lane & 15;
    const int quad = lane >> 4;

    f32x4 acc[4][4];
    #pragma unroll
    for (int mt = 0; mt < 4; ++mt)
        #pragma unroll
        for (int nt = 0; nt < 4; ++nt)
            acc[mt][nt] = (f32x4){0.f, 0.f, 0.f, 0.f};

    const int jt0 = wj >> 4;           // local Y tile base (0 or 4)
    const int it0 = wi >> 4;           // local X tile base (0 or 4)

    #pragma unroll
    for (int h = 0; h < 2; ++h) {
        bf16x8 Af[4], Bf[4];
        #pragma unroll
        for (int mt = 0; mt < 4; ++mt)   // A from Y tiles (m = j dim)
            Af[mt] = *(const bf16x8*)&lY[jt0 + mt][h][lane * 8];
        #pragma unroll
        for (int nt = 0; nt < 4; ++nt)   // B from X tiles (n = i dim)
            Bf[nt] = *(const bf16x8*)&lX[it0 + nt][h][lane * 8];
        #pragma unroll
        for (int mt = 0; mt < 4; ++mt)
            #pragma unroll
            for (int nt = 0; nt < 4; ++nt)
                acc[mt][nt] = __builtin_amdgcn_mfma_f32_16x16x32_bf16(
                    Af[mt], Bf[nt], acc[mt][nt], 0, 0, 0);
    }

    float nxv[4];
    float4 nyv[4];
    #pragma unroll
    for (int nt = 0; nt < 4; ++nt)
        nxv[nt] = nrmX[wi + nt * 16 + lm];
    #pragma unroll
    for (int mt = 0; mt < 4; ++mt)
        nyv[mt] = *(const float4*)&nrmY[wj + mt * 16 + quad * 4];

    #pragma unroll
    for (int nt = 0; nt < 4; ++nt) {
        const int i = ib + wi + nt * 16 + lm;
        unsigned short* Drow = Wt + ((size_t)b * NN + i) * NN + jb + wj;
        #pragma unroll
        for (int mt = 0; mt < 4; ++mt) {
            const float* nyp = (const float*)&nyv[mt];
            unsigned a[4];
            #pragma unroll
            for (int r = 0; r < 4; ++r) {
                float d2 = nyp[r] + nxv[nt] - 2.0f * acc[mt][nt][r];
                float w  = __builtin_amdgcn_exp2f(16.0f - LOG2E * sqrtf(fmaxf(d2, 0.f)));
                a[r] = __float_as_uint(w) + 0x8000u;   // round-half-up to bf16
            }
            uint2 pkt;
            pkt.x = (a[0] >> 16) | (a[1] & 0xFFFF0000u);
            pkt.y = (a[2] >> 16) | (a[3] & 0xFFFF0000u);
            *(uint2*)(Drow + mt * 16 + quad * 4) = pkt;
        }
    }
}

// ---------------------------------------------------------------------------
// Kernel 2: soft-DTW DP, exp-domain chain -- EXACT R0 code (the proven 65us
// version; R14-R17 alternatives all regressed). Two pipelined waves per
// batch, 4 rows/lane, log2-domain absolute handoff h via DPP + LDS.
// ---------------------------------------------------------------------------
static __device__ __forceinline__ float dpp_shr1(float x, float old) {
    return __int_as_float(__builtin_amdgcn_update_dpp(
        __float_as_int(old), __float_as_int(x), 0x138, 0xf, 0xf, false));
}
static __device__ __forceinline__ float dpp_shl1(float x) {
    return __int_as_float(__builtin_amdgcn_update_dpp(
        0, __float_as_int(x), 0x130, 0xf, 0xf, false));
}

static __device__ __forceinline__ void dtw_step4(
    bool W1, bool DOACT, bool DOGUARD, bool DOCLAMP, bool DOREN,
    int ss, int u, int t, const unsigned short* __restrict__ Wb, int ib,
    uint2* ring, float* L, float& diagHold, float& h, float& Otf,
    float& hbuf, float* __restrict__ h0)
{
    // intra-wave handoff: lane t gets lane t-1's h (lane 0: -inf)
    float recvH = dpp_shr1(h, NINF);
    if (W1) {
        recvH = (t == 0) ? hbuf : recvH;   // lane 0: cross-wave value from LDS
        hbuf  = dpp_shl1(hbuf);            // rotate: next step's value to lane 0
    }
    if (DOACT) { if (ss == t && (t > 0 || W1)) Otf = -recvH; }  // adopt scale

    const float up0   = __builtin_amdgcn_exp2f(fminf(recvH + Otf, 80.0f));
    const float diag0 = diagHold;          // 2^16 * F[row ib][j-1], stored dom.
    diagHold = up0 * 65536.0f;             // 2^16 * F[row ib][j] for next step

    const int j = ss - t + 1;
    const uint2 c = ring[u];

    // refill slot u for step ss+RING (unconditional; overrun reads dead data)
    {
        int jn = j + RING;
        if (DOCLAMP) jn = jn < 1 ? 1 : jn;
        ring[u] = *(const uint2*)(Wb + (size_t)(jn - 1) * NN + ib);
    }

    bool act = true;
    if (DOGUARD) act = (j >= 1) && (j <= NN);
    if (act) {
        float dd[4];                       // bf16 -> f32: shl/and, exact
        dd[0] = __uint_as_float(c.x << 16);
        dd[1] = __uint_as_float(c.x & 0xFFFF0000u);
        dd[2] = __uint_as_float(c.y << 16);
        dd[3] = __uint_as_float(c.y & 0xFFFF0000u);

        float pre[4], cc[4];
        pre[0] = diag0 + L[0];
        #pragma unroll
        for (int k = 1; k < 4; ++k)
            pre[k] = fmaf(65536.0f, L[k - 1], L[k]);
        #pragma unroll
        for (int k = 0; k < 4; ++k) cc[k] = dd[k] * pre[k];
        float r = up0;
        #pragma unroll
        for (int k = 0; k < 4; ++k) {      // serial chain: 4 fma
            r = fmaf(dd[k], r, cc[k]);
            L[k] = r;
        }

        if (DOREN) {   // branchless full normalization: max(L) -> [1,2)
            float m4 = fmaxf(fmaxf(L[0], L[1]), fmaxf(L[2], L[3]));
            const int   e  = (int)(__float_as_uint(m4) >> 23) - 127;
            const float sc = __uint_as_float((unsigned)(127 - e) << 23); // 2^-e
            #pragma unroll
            for (int k = 0; k < 4; ++k) L[k] *= sc;
            diagHold *= sc;
            Otf -= (float)e;
        }

        h = __builtin_amdgcn_logf(L[3]) - Otf;   // absolute log2-domain handoff
        if (!W1) h0[j] = h;                // publish row-boundary value
    }
}

static __device__ __forceinline__ void run_chunk(
    bool W1, bool ACT, bool GUARD, bool CLAMP, int base,
    int t, const unsigned short* __restrict__ Wb, int ib,
    uint2* ring, float* L, float& diagHold, float& h, float& Otf,
    float& hbuf, float* __restrict__ h0)
{
    for (int sb = 0; sb < 64; sb += RING)
        #pragma unroll
        for (int u = 0; u < RING; ++u)
            dtw_step4(W1, ACT, GUARD, CLAMP, (u & 1) == 1,
                      base + sb + u, u, t, Wb, ib, ring, L,
                      diagHold, h, Otf, hbuf, h0);
}

__global__ __launch_bounds__(128) void dtw_kernel(const unsigned short* __restrict__ Wt,
                                                  float* __restrict__ out) {
    __shared__ float h0[584];
    const int b    = blockIdx.x;
    const int tid  = threadIdx.x;
    const int t    = tid & 63;
    const int wave = tid >> 6;
    const unsigned short* __restrict__ Wb = Wt + (size_t)b * NN * NN;
    const int ib = wave * 256 + 4 * t;     // first owned row - 1

    float L[4] = {0.f, 0.f, 0.f, 0.f};     // F(boundary) = 0
    float diagHold = (wave == 0 && t == 0) ? 65536.0f : 0.0f; // 2^16*F[0][0]
    float h = NINF, Otf = 0.0f, hbuf = NINF;

    uint2 ring[RING];
    #pragma unroll
    for (int u = 0; u < RING; ++u) {
        int col = u - t + 1;
        col = col < 1 ? 1 : col;           // clamp; dead if OOB
        ring[u] = *(const uint2*)(Wb + (size_t)(col - 1) * NN + ib);
    }

    for (int wall = 0; wall < 11; ++wall) {
        const int ch = wave ? wall - 2 : wall;   // wave 1 lags 2 chunks
        if (wave == 0) {
            if (ch == 0)
                run_chunk(false, true,  true,  true,  0,      t, Wb, ib, ring, L, diagHold, h, Otf, hbuf, h0);
            else if (ch >= 1 && ch <= 7)
                run_chunk(false, false, false, false, ch*64,  t, Wb, ib, ring, L, diagHold, h, Otf, hbuf, h0);
            else if (ch == 8)
                run_chunk(false, false, true,  false, 512,    t, Wb, ib, ring, L, diagHold, h, Otf, hbuf, h0);
        } else {
            if (ch == 0)
                run_chunk(true,  true,  true,  true,  0,      t, Wb, ib, ring, L, diagHold, h, Otf, hbuf, h0);
            else if (ch >= 1 && ch <= 7)
                run_chunk(true,  false, false, false, ch*64,  t, Wb, ib, ring, L, diagHold, h, Otf, hbuf, h0);
            else if (ch == 8)
                run_chunk(true,  false, true,  false, 512,    t, Wb, ib, ring, L, diagHold, h, Otf, hbuf, h0);
        }
        __syncthreads();
        // preload wave 1's next-chunk boundary values (cols base+1..base+64)
        if (wave && wall >= 1 && wall <= 9)
            hbuf = h0[(wall - 1) * 64 + 1 + t];
    }

    // F[512][512] = 2^(16*1024) e^{-R}; h = log2 F (absolute)
    if (wave == 1 && t == 63) out[b] = (16384.0f - h) * LN2;
}

extern "C" void kernel_launch(void* const* d_in, const int* in_sizes, int n_in,
                              void* d_out, int out_size, void* d_ws, size_t ws_size,
                              hipStream_t stream) {
    const float* X = (const float*)d_in[0];
    const float* Y = (const float*)d_in[1];
    float* out = (float*)d_out;

    // workspace layout (ws >= 32 MB):
    //   [0, 32 MB)      Wt  : bf16 W matrix, layout [b][i][j]
    char* ws = (char*)d_ws;
    unsigned short* Wt = (unsigned short*)(ws);

    cdist_kernel<<<dim3(4, 4, NB), 256, 0, stream>>>(X, Y, Wt);
    dtw_kernel<<<NB, 128, 0, stream>>>(Wt, out);
}